// Round 11
// baseline (178.082 us; speedup 1.0000x reference)
//
#include <hip/hip_runtime.h>
#include <hip/hip_bf16.h>

#define B_N 16384
#define D_K 128

typedef __bf16 bf16x8 __attribute__((ext_vector_type(8)));
typedef float f32x4 __attribute__((ext_vector_type(4)));
typedef float f32x2 __attribute__((ext_vector_type(2)));

#if defined(__has_builtin)
#if __has_builtin(__builtin_amdgcn_exp2f)
#define EXP2F(x) __builtin_amdgcn_exp2f(x)
#else
#define EXP2F(x) exp2f(x)
#endif
#else
#define EXP2F(x) exp2f(x)
#endif

__device__ __forceinline__ void gload_lds16(const void* g, void* l) {
  __builtin_amdgcn_global_load_lds(
      (const __attribute__((address_space(1))) unsigned int*)g,
      (__attribute__((address_space(3))) unsigned int*)l, 16, 0, 0);
}

// ---------------- kernel 1: normalize rows, prescale by sqrt(1/(T*ln2)), build col weights
__global__ __launch_bounds__(256) void prep_kernel(
    const float* __restrict__ E, const int* __restrict__ labels,
    const int* __restrict__ mask, __hip_bfloat16* __restrict__ Ebf,
    float2* __restrict__ W)
{
  int tid = threadIdx.x;
  int gtid = blockIdx.x * 256 + tid;
  if (gtid < B_N) {
    int lb = labels[gtid];
    float wm = (mask[gtid] != 0) ? 1.0f : 0.0f;
    W[gtid] = make_float2((lb == 0) ? wm : 0.0f, wm);
  }
  int lane = tid & 63;
  int wid = gtid >> 6;
  const float2* E2 = (const float2*)E;
  __hip_bfloat162* O2 = (__hip_bfloat162*)Ebf;
  for (int row = wid; row < B_N; row += 4096) {
    float2 v = E2[row * 64 + lane];
    float ss = v.x * v.x + v.y * v.y;
    #pragma unroll
    for (int m = 1; m < 64; m <<= 1) ss += __shfl_xor(ss, m);
    // sqrt(14.426950408889634) = sqrt(1/(0.1*ln2)); folded into both operands
    float sc = 3.7982826f / fmaxf(sqrtf(ss), 1e-12f);
    __hip_bfloat162 h;
    h.x = __float2bfloat16(v.x * sc);
    h.y = __float2bfloat16(v.y * sc);
    O2[row * 64 + lane] = h;
  }
}

// ---------------- kernel 2: fused Gram + exp + masked row-sum, DIRECT-from-L2 B reads
// Ebf (4 MB) is fully L2-resident (FETCH=17MB @R10). LDS tile staging + per-tile
// vmcnt(0)+barrier rendezvous was pure overhead (Common-mistake #7 / m169).
// Now: zero in-loop sync; waves fully independent; b-frags read straight from L2
// (4 consecutive lanes share one 64B column segment = perfect cache-line coalescing).
template<bool DIAG>
__device__ __forceinline__ void tile_direct(
    const __hip_bfloat16* __restrict__ Ebf, const char* ldsW, const bf16x8 a[4][4],
    int C0loc, int colBase, int lane, int WR0, f32x2 acc[4][4])
{
  const int l15 = lane & 15, lg = lane >> 4;
  #pragma unroll
  for (int nf = 0; nf < 4; ++nf) {
    int col = nf * 16 + l15;
    int colg = colBase + C0loc + col;
    f32x2 wv = *(const f32x2*)(ldsW + ((C0loc + col) << 3));  // LDS broadcast
    const bf16x8* bp = (const bf16x8*)(Ebf + (size_t)colg * D_K + lg * 8);
    bf16x8 b0 = bp[0], b1 = bp[4], b2 = bp[8], b3 = bp[12];   // K-chunks kk*32
    f32x4 c[4];
    __builtin_amdgcn_s_setprio(1);
    #pragma unroll
    for (int mf = 0; mf < 4; ++mf) {
      f32x4 t = {0.f, 0.f, 0.f, 0.f};
      t = __builtin_amdgcn_mfma_f32_16x16x32_bf16(a[mf][0], b0, t, 0, 0, 0);
      t = __builtin_amdgcn_mfma_f32_16x16x32_bf16(a[mf][1], b1, t, 0, 0, 0);
      t = __builtin_amdgcn_mfma_f32_16x16x32_bf16(a[mf][2], b2, t, 0, 0, 0);
      t = __builtin_amdgcn_mfma_f32_16x16x32_bf16(a[mf][3], b3, t, 0, 0, 0);
      c[mf] = t;
    }
    __builtin_amdgcn_s_setprio(0);
    #pragma unroll
    for (int mf = 0; mf < 4; ++mf) {
      #pragma unroll
      for (int r = 0; r < 4; ++r) {
        float p = EXP2F(c[mf][r]);     // exp(sim/T), scale folded into operands
        if (DIAG) {
          int rowg = WR0 + mf * 16 + lg * 4 + r;  // verified C/D layout
          p = (rowg == colg) ? 0.0f : p;
        }
        acc[mf][r] += wv * p;          // v_pk_fma_f32: (label-0 sum, total sum)
      }
    }
  }
}

// (256,2) = 256-reg unified budget; 64-row/wave live ~176 regs (112 arch + acc).
// (256,3)/(256,4) spill catastrophically (R1/R3).
__global__ __launch_bounds__(256, 2) void gemm_kernel(
    const __hip_bfloat16* __restrict__ Ebf, const float2* __restrict__ W,
    float2* __restrict__ SW, int colsPerSplit)
{
  __shared__ alignas(16) char ldsW[8192];   // w(col) slice, cps <= 1024

  const int tid = threadIdx.x;
  const int lane = tid & 63;
  const int w = tid >> 6;
  const int R0 = blockIdx.x * 256;
  const int WR0 = R0 + w * 64;
  const int l15 = lane & 15, lg = lane >> 4;

  // A fragments: 4 m-frags x 4 k-steps, held in VGPRs for the whole col loop
  bf16x8 a[4][4];
  #pragma unroll
  for (int mf = 0; mf < 4; ++mf)
    #pragma unroll
    for (int kk = 0; kk < 4; ++kk) {
      int row = WR0 + mf * 16 + l15;
      a[mf][kk] = *(const bf16x8*)(Ebf + (size_t)row * D_K + kk * 32 + lg * 8);
    }

  const int colBase = blockIdx.y * colsPerSplit;
  const int nt = colsPerSplit >> 6;

  // stage W slice to LDS (broadcast source); the ONLY barrier in the kernel
  {
    const char* wsrc = (const char*)(W + colBase);
    for (int i = tid; i < (colsPerSplit >> 1); i += 256)
      gload_lds16(wsrc + i * 16, ldsW + i * 16);
  }
  asm volatile("s_waitcnt vmcnt(0)" ::: "memory");
  __builtin_amdgcn_s_barrier();

  f32x2 acc[4][4] = {};
  for (int t = 0; t < nt; ++t) {
    const int C0 = colBase + (t << 6);
    const bool diag = (C0 < R0 + 256) && (C0 + 64 > R0);
    if (diag) tile_direct<true >(Ebf, ldsW, a, t << 6, colBase, lane, WR0, acc);
    else      tile_direct<false>(Ebf, ldsW, a, t << 6, colBase, lane, WR0, acc);
  }

  // reduce the 16 lanes (same row-group, different col subsets), then store
  #pragma unroll
  for (int mf = 0; mf < 4; ++mf) {
    #pragma unroll
    for (int r = 0; r < 4; ++r) {
      float s0 = acc[mf][r].x, tt = acc[mf][r].y;
      #pragma unroll
      for (int m = 1; m < 16; m <<= 1) {
        s0 += __shfl_xor(s0, m);
        tt += __shfl_xor(tt, m);
      }
      if (l15 == 0) {
        int rowg = WR0 + mf * 16 + lg * 4 + r;
        SW[(size_t)blockIdx.y * B_N + rowg] = make_float2(s0, tt);
      }
    }
  }
}

// ---------------- kernel 3a: per-row loss, 256 blocks x 64 rows, deterministic
__global__ __launch_bounds__(256) void loss_part(
    const int* __restrict__ labels, const int* __restrict__ mask,
    const float2* __restrict__ SW, int NS, float2* __restrict__ partial)
{
  __shared__ int sc0[4], sc1[4];
  __shared__ float st[4], sn[4];
  __shared__ float2 red[256];
  int tid = threadIdx.x, lane = tid & 63, wv = tid >> 6;

  // redundant full histogram per block (L2-resident, deterministic)
  int c0 = 0, c1 = 0;
  for (int i = tid; i < B_N; i += 256) {
    if (mask[i] != 0) { if (labels[i] == 0) c0++; else c1++; }
  }
  #pragma unroll
  for (int m = 1; m < 64; m <<= 1) { c0 += __shfl_xor(c0, m); c1 += __shfl_xor(c1, m); }
  if (lane == 0) { sc0[wv] = c0; sc1[wv] = c1; }
  __syncthreads();
  int cnt0 = sc0[0] + sc0[1] + sc0[2] + sc0[3];
  int cnt1 = sc1[0] + sc1[1] + sc1[2] + sc1[3];

  // 64 rows per block; 4 threads per row (slot quarters), fixed-order combine
  int r = blockIdx.x * 64 + (tid & 63);
  int q = tid >> 6;
  float s0 = 0.f, tt = 0.f;
  for (int s = q; s < NS; s += 4) {
    float2 v = SW[(size_t)s * B_N + r];
    s0 += v.x; tt += v.y;
  }
  red[tid] = make_float2(s0, tt);
  __syncthreads();

  float tot = 0.f, nv = 0.f;
  if (q == 0) {
    float2 va = red[tid], vb = red[64 + tid], vc = red[128 + tid], vd = red[192 + tid];
    s0 = va.x + vb.x + vc.x + vd.x;
    tt = va.y + vb.y + vc.y + vd.y;
    int lb = labels[r];
    float pos = (lb == 0) ? s0 : (tt - s0);
    int cnt = (lb == 0) ? cnt0 : cnt1;
    if (mask[r] != 0 && cnt > 1) {
      // den = pos + neg = tt (diag excluded); loss = log(den+EPS) - log(pos)
      tot = logf(tt + 1e-8f) - logf(pos);
      nv = 1.f;
    }
  }
  #pragma unroll
  for (int m = 1; m < 64; m <<= 1) { tot += __shfl_xor(tot, m); nv += __shfl_xor(nv, m); }
  if (lane == 0) { st[wv] = tot; sn[wv] = nv; }
  __syncthreads();
  if (tid == 0) {
    partial[blockIdx.x] = make_float2(st[0] + st[1] + st[2] + st[3],
                                      sn[0] + sn[1] + sn[2] + sn[3]);
  }
}

// ---------------- kernel 3b: final deterministic reduce (one wave)
__global__ __launch_bounds__(64) void loss_final(
    const float2* __restrict__ partial, int nb, float* __restrict__ out)
{
  int lane = threadIdx.x;
  float t = 0.f, n = 0.f;
  for (int i = lane; i < nb; i += 64) {
    float2 v = partial[i];
    t += v.x; n += v.y;
  }
  #pragma unroll
  for (int m = 1; m < 64; m <<= 1) { t += __shfl_xor(t, m); n += __shfl_xor(n, m); }
  if (lane == 0) out[0] = (n > 0.f) ? t / fmaxf(n, 1.f) : 0.f;
}

extern "C" void kernel_launch(void* const* d_in, const int* in_sizes, int n_in,
                              void* d_out, int out_size, void* d_ws, size_t ws_size,
                              hipStream_t stream)
{
  const float* E = (const float*)d_in[0];
  const int* labels = (const int*)d_in[1];
  const int* mask = (const int*)d_in[2];

  char* ws = (char*)d_ws;
  __hip_bfloat16* Ebf = (__hip_bfloat16*)ws;                       // 4 MB
  float2* W = (float2*)(ws + (size_t)B_N * D_K * 2);               // 128 KB
  float2* SW = (float2*)(ws + (size_t)B_N * D_K * 2 + (size_t)B_N * 8);
  size_t base = (size_t)B_N * D_K * 2 + (size_t)B_N * 8;

  int NS = 16;  // col splits; shrink if workspace tight (ldsW sized for cps<=1024)
  while (NS > 1 && base + (size_t)NS * B_N * 8 + 4096 > ws_size) NS >>= 1;
  int cps = B_N / NS;
  float2* partial = (float2*)(ws + base + (size_t)NS * B_N * 8);

  prep_kernel<<<1024, 256, 0, stream>>>(E, labels, mask, Ebf, W);
  dim3 g2(B_N / 256, NS);
  gemm_kernel<<<g2, 256, 0, stream>>>(Ebf, W, SW, cps);
  loss_part<<<B_N / 64, 256, 0, stream>>>(labels, mask, SW, NS, partial);
  loss_final<<<1, 64, 0, stream>>>(partial, B_N / 64, (float*)d_out);
}

// Round 12
// 127.280 us; speedup vs baseline: 1.3991x; 1.3991x over previous
//
#include <hip/hip_runtime.h>
#include <hip/hip_bf16.h>

#define B_N 16384
#define D_K 128
#define BM 128   // rows per block: 4 waves x 32 rows (3-waves/SIMD geometry)

typedef __bf16 bf16x8 __attribute__((ext_vector_type(8)));
typedef float f32x4 __attribute__((ext_vector_type(4)));
typedef float f32x2 __attribute__((ext_vector_type(2)));

#if defined(__has_builtin)
#if __has_builtin(__builtin_amdgcn_exp2f)
#define EXP2F(x) __builtin_amdgcn_exp2f(x)
#else
#define EXP2F(x) exp2f(x)
#endif
#else
#define EXP2F(x) exp2f(x)
#endif

__device__ __forceinline__ void gload_lds16(const void* g, void* l) {
  __builtin_amdgcn_global_load_lds(
      (const __attribute__((address_space(1))) unsigned int*)g,
      (__attribute__((address_space(3))) unsigned int*)l, 16, 0, 0);
}

// ---------------- kernel 1: normalize rows, prescale by sqrt(1/(T*ln2)), build col weights
__global__ __launch_bounds__(256) void prep_kernel(
    const float* __restrict__ E, const int* __restrict__ labels,
    const int* __restrict__ mask, __hip_bfloat16* __restrict__ Ebf,
    float2* __restrict__ W)
{
  int tid = threadIdx.x;
  int gtid = blockIdx.x * 256 + tid;
  if (gtid < B_N) {
    int lb = labels[gtid];
    float wm = (mask[gtid] != 0) ? 1.0f : 0.0f;
    W[gtid] = make_float2((lb == 0) ? wm : 0.0f, wm);
  }
  int lane = tid & 63;
  int wid = gtid >> 6;
  const float2* E2 = (const float2*)E;
  __hip_bfloat162* O2 = (__hip_bfloat162*)Ebf;
  for (int row = wid; row < B_N; row += 4096) {
    float2 v = E2[row * 64 + lane];
    float ss = v.x * v.x + v.y * v.y;
    #pragma unroll
    for (int m = 1; m < 64; m <<= 1) ss += __shfl_xor(ss, m);
    // sqrt(14.426950408889634) = sqrt(1/(0.1*ln2)); folded into both operands
    float sc = 3.7982826f / fmaxf(sqrtf(ss), 1e-12f);
    __hip_bfloat162 h;
    h.x = __float2bfloat16(v.x * sc);
    h.y = __float2bfloat16(v.y * sc);
    O2[row * 64 + lane] = h;
  }
}

// ---------------- kernel 2: fused Gram + exp + masked row-sum
// R4-geometry revisit with both of its killers fixed:
//  - l15 swizzle (R10): b-read bank conflicts 4.2M -> 0 (verified)
//  - W in LDS (R5+): no in-loop global W loads
// 32 rows/wave halves register footprint -> (256,3) fits (R4 bench: VGPR 80,
// FETCH 17MB, no spill) -> 3 blocks/CU, 3 waves/SIMD of pipe-overlap capacity.
template<bool DIAG>
__device__ __forceinline__ void tile_compute(
    const char* lds, const char* ldsW, const bf16x8 a[2][4],
    int C0loc, int colBase, int lane, int WR0, f32x2 acc[2][4])
{
  const int l15 = lane & 15, lg = lane >> 4;
  #pragma unroll
  for (int nf = 0; nf < 4; ++nf) {
    int col = nf * 16 + l15;
    int colg = colBase + C0loc + col;
    f32x2 wv = *(const f32x2*)(ldsW + ((C0loc + col) << 3));  // LDS broadcast
    bf16x8 b[4];
    #pragma unroll
    for (int kk = 0; kk < 4; ++kk) {
      int addr = col * 256 + (((kk * 4 + lg) ^ l15) << 4);    // 2-way banks (free)
      b[kk] = *(const bf16x8*)(lds + addr);
    }
    f32x4 c[2];
    __builtin_amdgcn_s_setprio(1);
    #pragma unroll
    for (int mf = 0; mf < 2; ++mf) {
      f32x4 t = {0.f, 0.f, 0.f, 0.f};
      #pragma unroll
      for (int kk = 0; kk < 4; ++kk)
        t = __builtin_amdgcn_mfma_f32_16x16x32_bf16(a[mf][kk], b[kk], t, 0, 0, 0);
      c[mf] = t;
    }
    __builtin_amdgcn_s_setprio(0);
    #pragma unroll
    for (int mf = 0; mf < 2; ++mf) {
      #pragma unroll
      for (int r = 0; r < 4; ++r) {
        float p = EXP2F(c[mf][r]);     // exp(sim/T), scale folded into operands
        if (DIAG) {
          int rowg = WR0 + mf * 16 + lg * 4 + r;  // verified C/D layout
          p = (rowg == colg) ? 0.0f : p;
        }
        acc[mf][r] += wv * p;          // v_pk_fma_f32: (label-0 sum, total sum)
      }
    }
  }
}

__global__ __launch_bounds__(256, 3) void gemm_kernel(
    const __hip_bfloat16* __restrict__ Ebf, const float2* __restrict__ W,
    float2* __restrict__ SW, int colsPerSplit)
{
  __shared__ alignas(16) char smem[40960];
  char* ldsW  = smem;            // 8 KB: w(col) for cps<=1024
  char* tiles = smem + 8192;     // 2 x 16 KB double buffer

  const int tid = threadIdx.x;
  const int lane = tid & 63;
  const int w = tid >> 6;
  const int R0 = blockIdx.x * BM;
  const int WR0 = R0 + w * 32;   // 32 rows per wave
  const int l15 = lane & 15, lg = lane >> 4;

  // A fragments: 2 m-frags x 4 k-steps
  bf16x8 a[2][4];
  #pragma unroll
  for (int mf = 0; mf < 2; ++mf)
    #pragma unroll
    for (int kk = 0; kk < 4; ++kk) {
      int row = WR0 + mf * 16 + l15;
      a[mf][kk] = *(const bf16x8*)(Ebf + (size_t)row * D_K + kk * 32 + lg * 8);
    }

  // staging offsets: linear LDS dest, full-4-bit inverse swizzle on global source
  int goff[4], loff[4];
  #pragma unroll
  for (int i = 0; i < 4; ++i) {
    int q = i * 4 + w;            // 1KB chunk-group id 0..15 (16KB tile)
    int col = q * 4 + lg;         // tile-local col this lane feeds (0..63)
    int cc = l15 ^ (col & 15);    // inverse of the l15 read swizzle
    goff[i] = col * D_K + cc * 8; // bf16 elements
    loff[i] = q * 1024;           // wave-uniform LDS base (bytes)
  }

  f32x2 acc[2][4] = {};
  const int colBase = blockIdx.y * colsPerSplit;
  const int nt = colsPerSplit >> 6;

  // prologue: stage W slice + tile 0, drain, rendezvous
  {
    const char* wsrc = (const char*)(W + colBase);
    for (int i = tid; i < (colsPerSplit >> 1); i += 256)
      gload_lds16(wsrc + i * 16, ldsW + i * 16);
    const __hip_bfloat16* src0 = Ebf + (size_t)colBase * D_K;
    #pragma unroll
    for (int i = 0; i < 4; ++i) gload_lds16(src0 + goff[i], tiles + loff[i]);
  }
  asm volatile("s_waitcnt vmcnt(0)" ::: "memory");
  __builtin_amdgcn_s_barrier();

  int cur = 0;
  for (int t = 0; t < nt; ++t) {
    if (t + 1 < nt) {   // prefetch next tile into the other buffer (2-phase)
      const __hip_bfloat16* src = Ebf + (size_t)(colBase + ((t + 1) << 6)) * D_K;
      char* dst = tiles + ((cur ^ 1) << 14);
      #pragma unroll
      for (int i = 0; i < 4; ++i) gload_lds16(src + goff[i], dst + loff[i]);
    }
    const int C0loc = t << 6;
    const int Cg = colBase + C0loc;
    const bool diag = (Cg < R0 + BM) && (Cg + 64 > R0);
    if (diag) tile_compute<true >(tiles + (cur << 14), ldsW, a, C0loc, colBase, lane, WR0, acc);
    else      tile_compute<false>(tiles + (cur << 14), ldsW, a, C0loc, colBase, lane, WR0, acc);
    asm volatile("s_waitcnt vmcnt(0)" ::: "memory");
    __builtin_amdgcn_s_barrier();
    cur ^= 1;
  }

  // reduce the 16 lanes (same row-group, different col subsets), then store
  #pragma unroll
  for (int mf = 0; mf < 2; ++mf) {
    #pragma unroll
    for (int r = 0; r < 4; ++r) {
      float s0 = acc[mf][r].x, tt = acc[mf][r].y;
      #pragma unroll
      for (int m = 1; m < 16; m <<= 1) {
        s0 += __shfl_xor(s0, m);
        tt += __shfl_xor(tt, m);
      }
      if (l15 == 0) {
        int rowg = WR0 + mf * 16 + lg * 4 + r;
        SW[(size_t)blockIdx.y * B_N + rowg] = make_float2(s0, tt);
      }
    }
  }
}

// ---------------- kernel 3a: per-row loss, 256 blocks x 64 rows, deterministic
__global__ __launch_bounds__(256) void loss_part(
    const int* __restrict__ labels, const int* __restrict__ mask,
    const float2* __restrict__ SW, int NS, float2* __restrict__ partial)
{
  __shared__ int sc0[4], sc1[4];
  __shared__ float st[4], sn[4];
  __shared__ float2 red[256];
  int tid = threadIdx.x, lane = tid & 63, wv = tid >> 6;

  // redundant full histogram per block (L2-resident, deterministic)
  int c0 = 0, c1 = 0;
  for (int i = tid; i < B_N; i += 256) {
    if (mask[i] != 0) { if (labels[i] == 0) c0++; else c1++; }
  }
  #pragma unroll
  for (int m = 1; m < 64; m <<= 1) { c0 += __shfl_xor(c0, m); c1 += __shfl_xor(c1, m); }
  if (lane == 0) { sc0[wv] = c0; sc1[wv] = c1; }
  __syncthreads();
  int cnt0 = sc0[0] + sc0[1] + sc0[2] + sc0[3];
  int cnt1 = sc1[0] + sc1[1] + sc1[2] + sc1[3];

  // 64 rows per block; 4 threads per row (slot quarters), fixed-order combine
  int r = blockIdx.x * 64 + (tid & 63);
  int q = tid >> 6;
  float s0 = 0.f, tt = 0.f;
  for (int s = q; s < NS; s += 4) {
    float2 v = SW[(size_t)s * B_N + r];
    s0 += v.x; tt += v.y;
  }
  red[tid] = make_float2(s0, tt);
  __syncthreads();

  float tot = 0.f, nv = 0.f;
  if (q == 0) {
    float2 va = red[tid], vb = red[64 + tid], vc = red[128 + tid], vd = red[192 + tid];
    s0 = va.x + vb.x + vc.x + vd.x;
    tt = va.y + vb.y + vc.y + vd.y;
    int lb = labels[r];
    float pos = (lb == 0) ? s0 : (tt - s0);
    int cnt = (lb == 0) ? cnt0 : cnt1;
    if (mask[r] != 0 && cnt > 1) {
      // den = pos + neg = tt (diag excluded); loss = log(den+EPS) - log(pos)
      tot = logf(tt + 1e-8f) - logf(pos);
      nv = 1.f;
    }
  }
  #pragma unroll
  for (int m = 1; m < 64; m <<= 1) { tot += __shfl_xor(tot, m); nv += __shfl_xor(nv, m); }
  if (lane == 0) { st[wv] = tot; sn[wv] = nv; }
  __syncthreads();
  if (tid == 0) {
    partial[blockIdx.x] = make_float2(st[0] + st[1] + st[2] + st[3],
                                      sn[0] + sn[1] + sn[2] + sn[3]);
  }
}

// ---------------- kernel 3b: final deterministic reduce (one wave)
__global__ __launch_bounds__(64) void loss_final(
    const float2* __restrict__ partial, int nb, float* __restrict__ out)
{
  int lane = threadIdx.x;
  float t = 0.f, n = 0.f;
  for (int i = lane; i < nb; i += 64) {
    float2 v = partial[i];
    t += v.x; n += v.y;
  }
  #pragma unroll
  for (int m = 1; m < 64; m <<= 1) { t += __shfl_xor(t, m); n += __shfl_xor(n, m); }
  if (lane == 0) out[0] = (n > 0.f) ? t / fmaxf(n, 1.f) : 0.f;
}

extern "C" void kernel_launch(void* const* d_in, const int* in_sizes, int n_in,
                              void* d_out, int out_size, void* d_ws, size_t ws_size,
                              hipStream_t stream)
{
  const float* E = (const float*)d_in[0];
  const int* labels = (const int*)d_in[1];
  const int* mask = (const int*)d_in[2];

  char* ws = (char*)d_ws;
  __hip_bfloat16* Ebf = (__hip_bfloat16*)ws;                       // 4 MB
  float2* W = (float2*)(ws + (size_t)B_N * D_K * 2);               // 128 KB
  float2* SW = (float2*)(ws + (size_t)B_N * D_K * 2 + (size_t)B_N * 8);
  size_t base = (size_t)B_N * D_K * 2 + (size_t)B_N * 8;

  int NS = 16;  // col splits; shrink if workspace tight (ldsW sized for cps<=1024)
  while (NS > 1 && base + (size_t)NS * B_N * 8 + 4096 > ws_size) NS >>= 1;
  int cps = B_N / NS;
  float2* partial = (float2*)(ws + base + (size_t)NS * B_N * 8);

  prep_kernel<<<1024, 256, 0, stream>>>(E, labels, mask, Ebf, W);
  dim3 g2(B_N / BM, NS);   // (128, 16) = 2048 blocks, ~8 supplied/CU, 3 resident
  gemm_kernel<<<g2, 256, 0, stream>>>(Ebf, W, SW, cps);
  loss_part<<<B_N / 64, 256, 0, stream>>>(labels, mask, SW, NS, partial);
  loss_final<<<1, 64, 0, stream>>>(partial, B_N / 64, (float*)d_out);
}